// Round 1
// baseline (304.216 us; speedup 1.0000x reference)
//
#include <hip/hip_runtime.h>
#include <stdint.h>

#define B_   2
#define S_   2048
#define D_   1024
#define H_   16
#define HD_  64
#define NTOK (B_ * S_)   // 4096

typedef unsigned short u16;
typedef __bf16 bf16x8 __attribute__((ext_vector_type(8)));
typedef float  f32x4  __attribute__((ext_vector_type(4)));

// ---- workspace layout (bytes) ----
#define OFF_FLAG ((size_t)0)
#define OFF_BIAS ((size_t)64)                       // 4 * 1024 fp32 = 16 KB
#define OFF_X    ((size_t)32768)
#define SZ_X     ((size_t)NTOK * D_ * 2)            // 8 MB
#define OFF_W    (OFF_X + SZ_X)                     // Wq,Wk,Wv,Wo bf16, 2 MB each
#define SZ_W     ((size_t)D_ * D_ * 2)
#define OFF_Q    (OFF_W + 4 * SZ_W)
#define SZ_T     ((size_t)NTOK * D_ * 2)            // 8 MB per tensor
#define OFF_K2   (OFF_Q + SZ_T)
#define OFF_VT   (OFF_K2 + SZ_T)
#define OFF_AO   (OFF_VT + SZ_T)

__device__ __forceinline__ float bf2f(u16 h) {
    union { uint32_t u; float f; } c; c.u = ((uint32_t)h) << 16; return c.f;
}
__device__ __forceinline__ u16 f2bf(float f) {
    union { float f; uint32_t u; } c; c.f = f;
    uint32_t r = c.u + 0x7fffu + ((c.u >> 16) & 1u);   // RNE
    return (u16)(r >> 16);
}
__device__ __forceinline__ void glds16(const u16* g, u16* l) {
    __builtin_amdgcn_global_load_lds(
        (const __attribute__((address_space(1))) uint32_t*)g,
        (__attribute__((address_space(3))) uint32_t*)l,
        16, 0, 0);
}
__device__ __forceinline__ f32x4 mfma16(bf16x8 a, bf16x8 b, f32x4 c) {
    return __builtin_amdgcn_mfma_f32_16x16x32_bf16(a, b, c, 0, 0, 0);
}

// ---- 1-block dtype detector: even-index bf16s of fp32 data are garbage ----
__global__ void detect_kernel(const void* wq, char* ws) {
    __shared__ int ok;
    if (threadIdx.x == 0) ok = 1;
    __syncthreads();
    const u16* p = (const u16*)wq;
    bool bad = false;
    for (int j = 0; j < 8; ++j) {
        float v = bf2f(p[(threadIdx.x * 8 + j) * 2]);   // even bf16 index
        if (!(v > -1.0f && v < 1.0f)) bad = true;       // catches NaN too
    }
    if (bad) ok = 0;
    __syncthreads();
    if (threadIdx.x == 0) *(int*)(ws + OFF_FLAG) = ok;  // 1 => data is bf16
}

// ---- normalize all float tensors into ws (bf16 mats, fp32 biases) ----
__global__ void convert_kernel(const void* x, const void* wq, const void* wk,
                               const void* wv, const void* wo,
                               const void* bq, const void* bk, const void* bv,
                               const void* bo, char* ws) {
    const int is_bf16 = *(const int*)(ws + OFF_FLAG);
    u16* Xd = (u16*)(ws + OFF_X);
    u16* Wd = (u16*)(ws + OFF_W);
    float* Bd = (float*)(ws + OFF_BIAS);
    const uint32_t NX = (uint32_t)NTOK * D_;     // 2^22
    const uint32_t NW = (uint32_t)D_ * D_;       // 2^20
    const uint32_t total = NX + 4 * NW + 4 * D_;
    for (uint32_t i = blockIdx.x * 256u + threadIdx.x; i < total;
         i += gridDim.x * 256u) {
        if (i < NX + 4 * NW) {
            const void* src; uint32_t si; u16* dst;
            if (i < NX) { src = x; si = i; dst = Xd + i; }
            else {
                uint32_t j = i - NX;
                uint32_t w = j >> 20; si = j & (NW - 1u);
                src = (w == 0) ? wq : (w == 1) ? wk : (w == 2) ? wv : wo;
                dst = Wd + j;
            }
            *dst = is_bf16 ? ((const u16*)src)[si] : f2bf(((const float*)src)[si]);
        } else {
            uint32_t j = i - NX - 4 * NW;
            uint32_t w = j >> 10; uint32_t si = j & (D_ - 1u);
            const void* src = (w == 0) ? bq : (w == 1) ? bk : (w == 2) ? bv : bo;
            Bd[j] = is_bf16 ? bf2f(((const u16*)src)[si]) : ((const float*)src)[si];
        }
    }
}

// ---- fused QKV projection: C[t][o] = X[t][:] . W[o][:] + b[o] (bt-GEMM) ----
// z=0 -> Q[b,h,s,hd] (pre-scaled 1/8); z=1 -> K[b,h,s,hd]; z=2 -> V^T[b,h,hd,s]
__global__ void qkv_gemm(char* ws) {
    __shared__ alignas(16) u16 As[128 * 32];
    __shared__ alignas(16) u16 Bs[128 * 32];
    const int z = blockIdx.z;
    const u16* A    = (const u16*)(ws + OFF_X);
    const u16* Bt   = (const u16*)(ws + OFF_W + (size_t)z * SZ_W);
    const float* bias = (const float*)(ws + OFF_BIAS) + z * D_;
    u16* Qd  = (u16*)(ws + OFF_Q);
    u16* Kd  = (u16*)(ws + OFF_K2);
    u16* Vtd = (u16*)(ws + OFF_VT);

    const int tid = threadIdx.x, lane = tid & 63, wave = tid >> 6;
    const int wm = (wave & 1) * 64, wn = (wave >> 1) * 64;
    const int m0 = blockIdx.y * 128, n0 = blockIdx.x * 128;
    const int lr = lane & 15, quad = lane >> 4, kq = quad * 8;
    const int srow = tid >> 2, scol = (tid & 3) * 8;

    f32x4 acc[4][4];
#pragma unroll
    for (int i = 0; i < 4; i++)
#pragma unroll
        for (int j = 0; j < 4; j++) acc[i][j] = (f32x4){0.f, 0.f, 0.f, 0.f};

    const u16* Ag0 = A  + (size_t)(m0 + srow)      * D_ + scol;
    const u16* Ag1 = A  + (size_t)(m0 + srow + 64) * D_ + scol;
    const u16* Bg0 = Bt + (size_t)(n0 + srow)      * D_ + scol;
    const u16* Bg1 = Bt + (size_t)(n0 + srow + 64) * D_ + scol;

    for (int k0 = 0; k0 < D_; k0 += 32) {
        glds16(Ag0 + k0, &As[tid * 8]);
        glds16(Ag1 + k0, &As[2048 + tid * 8]);
        glds16(Bg0 + k0, &Bs[tid * 8]);
        glds16(Bg1 + k0, &Bs[2048 + tid * 8]);
        __syncthreads();
        bf16x8 a[4], b[4];
#pragma unroll
        for (int i = 0; i < 4; i++) a[i] = *(const bf16x8*)&As[(wm + i * 16 + lr) * 32 + kq];
#pragma unroll
        for (int j = 0; j < 4; j++) b[j] = *(const bf16x8*)&Bs[(wn + j * 16 + lr) * 32 + kq];
#pragma unroll
        for (int i = 0; i < 4; i++)
#pragma unroll
            for (int j = 0; j < 4; j++) acc[i][j] = mfma16(a[i], b[j], acc[i][j]);
        __syncthreads();
    }
#pragma unroll
    for (int i = 0; i < 4; i++) {
        const int row_b = m0 + wm + i * 16 + quad * 4;
#pragma unroll
        for (int j = 0; j < 4; j++) {
            const int col = n0 + wn + j * 16 + lr;
            const float bv_ = bias[col];
            const int h = col >> 6, hd = col & 63;
#pragma unroll
            for (int r = 0; r < 4; r++) {
                const int row = row_b + r;
                const int bb = row >> 11, s = row & 2047;
                const float v = acc[i][j][r] + bv_;
                if (z == 0)
                    Qd[(((size_t)(bb * H_ + h)) * S_ + s) * HD_ + hd] = f2bf(v * 0.125f);
                else if (z == 1)
                    Kd[(((size_t)(bb * H_ + h)) * S_ + s) * HD_ + hd] = f2bf(v);
                else
                    Vtd[(((size_t)(bb * H_ + h)) * HD_ + hd) * S_ + s] = f2bf(v);
            }
        }
    }
}

// ---- flash attention: 64 queries/block (16/wave), 64-key tiles ----
__global__ void attn_kernel(char* ws, const int* mask) {
    __shared__ alignas(16) u16 Ks[64 * 64];    // [key][hd]
    __shared__ alignas(16) u16 Vts[64 * 64];   // [hd][key]
    __shared__ alignas(16) u16 Ps[4][16 * 64]; // per-wave P [q][key]

    const u16* Qb  = (const u16*)(ws + OFF_Q);
    const u16* Kb  = (const u16*)(ws + OFF_K2);
    const u16* Vtb = (const u16*)(ws + OFF_VT);
    u16* AO = (u16*)(ws + OFF_AO);

    const int tid = threadIdx.x, lane = tid & 63, wave = tid >> 6;
    const int bh = blockIdx.y, b = bh >> 4, h = bh & 15;
    const int q0 = blockIdx.x * 64;
    const int lr = lane & 15, quad = lane >> 4, kq = quad * 8;
    const int srow = tid >> 3, sseg = (tid & 7) * 8;

    const u16* Qbh  = Qb  + (size_t)bh * S_ * HD_;
    const u16* Kbh  = Kb  + (size_t)bh * S_ * HD_;
    const u16* Vbh  = Vtb + (size_t)bh * HD_ * S_;

    const int qrow = q0 + wave * 16 + lr;
    bf16x8 qf0 = *(const bf16x8*)&Qbh[(size_t)qrow * HD_ + kq];
    bf16x8 qf1 = *(const bf16x8*)&Qbh[(size_t)qrow * HD_ + 32 + kq];

    float m_i[4], l_i[4];
    f32x4 oacc[4];
#pragma unroll
    for (int r = 0; r < 4; r++) { m_i[r] = -1e30f; l_i[r] = 0.f; }
#pragma unroll
    for (int j = 0; j < 4; j++) oacc[j] = (f32x4){0.f, 0.f, 0.f, 0.f};

    for (int kt = 0; kt < S_ / 64; ++kt) {
        const int k0 = kt * 64;
        glds16(&Kbh[(size_t)(k0 + srow) * HD_ + sseg],        &Ks[tid * 8]);
        glds16(&Kbh[(size_t)(k0 + srow + 32) * HD_ + sseg],   &Ks[2048 + tid * 8]);
        glds16(&Vbh[(size_t)srow * S_ + k0 + sseg],           &Vts[tid * 8]);
        glds16(&Vbh[(size_t)(srow + 32) * S_ + k0 + sseg],    &Vts[2048 + tid * 8]);
        __syncthreads();

        // S = Q K^T (Q pre-scaled); C-layout: col=key j*16+lr, row=q quad*4+r
        f32x4 sc[4];
#pragma unroll
        for (int j = 0; j < 4; j++) {
            bf16x8 kf0 = *(const bf16x8*)&Ks[(j * 16 + lr) * 64 + kq];
            bf16x8 kf1 = *(const bf16x8*)&Ks[(j * 16 + lr) * 64 + 32 + kq];
            sc[j] = mfma16(qf0, kf0, (f32x4){0.f, 0.f, 0.f, 0.f});
            sc[j] = mfma16(qf1, kf1, sc[j]);
            const int key = k0 + j * 16 + lr;
            if (mask[b * S_ + key] == 0) {
#pragma unroll
                for (int r = 0; r < 4; r++) sc[j][r] = -1e9f;
            }
        }
        // online softmax per row (rows live on the quad's 16 lanes)
        float mnew[4], alpha[4], rs[4];
#pragma unroll
        for (int r = 0; r < 4; r++) {
            float mx = fmaxf(fmaxf(sc[0][r], sc[1][r]), fmaxf(sc[2][r], sc[3][r]));
#pragma unroll
            for (int d = 1; d < 16; d <<= 1) mx = fmaxf(mx, __shfl_xor(mx, d, 64));
            mnew[r] = fmaxf(m_i[r], mx);
            alpha[r] = __expf(m_i[r] - mnew[r]);
            rs[r] = 0.f;
        }
#pragma unroll
        for (int j = 0; j < 4; j++)
#pragma unroll
            for (int r = 0; r < 4; r++) {
                float p = __expf(sc[j][r] - mnew[r]);
                sc[j][r] = p; rs[r] += p;
            }
#pragma unroll
        for (int r = 0; r < 4; r++) {
#pragma unroll
            for (int d = 1; d < 16; d <<= 1) rs[r] += __shfl_xor(rs[r], d, 64);
            l_i[r] = l_i[r] * alpha[r] + rs[r];
            m_i[r] = mnew[r];
        }
#pragma unroll
        for (int j = 0; j < 4; j++)
#pragma unroll
            for (int r = 0; r < 4; r++) oacc[j][r] *= alpha[r];

        // P: C-layout -> A-layout via wave-private LDS (bf16)
        u16* Pw = &Ps[wave][0];
#pragma unroll
        for (int j = 0; j < 4; j++)
#pragma unroll
            for (int r = 0; r < 4; r++)
                Pw[(quad * 4 + r) * 64 + j * 16 + lr] = f2bf(sc[j][r]);
        bf16x8 pf0 = *(const bf16x8*)&Pw[lr * 64 + kq];
        bf16x8 pf1 = *(const bf16x8*)&Pw[lr * 64 + 32 + kq];
#pragma unroll
        for (int j = 0; j < 4; j++) {
            bf16x8 vf0 = *(const bf16x8*)&Vts[(j * 16 + lr) * 64 + kq];
            bf16x8 vf1 = *(const bf16x8*)&Vts[(j * 16 + lr) * 64 + 32 + kq];
            oacc[j] = mfma16(pf0, vf0, oacc[j]);
            oacc[j] = mfma16(pf1, vf1, oacc[j]);
        }
        __syncthreads();
    }
#pragma unroll
    for (int r = 0; r < 4; r++) {
        const float inv = 1.0f / l_i[r];
        const int q = q0 + wave * 16 + quad * 4 + r;
#pragma unroll
        for (int j = 0; j < 4; j++)
            AO[(size_t)(b * S_ + q) * D_ + h * HD_ + j * 16 + lr] = f2bf(oacc[j][r] * inv);
    }
}

// ---- output projection: out = AO . Wo^T + bo (store per dtype flag) ----
__global__ void out_gemm(char* ws, void* dout) {
    __shared__ alignas(16) u16 As[128 * 32];
    __shared__ alignas(16) u16 Bs[128 * 32];
    const u16* A  = (const u16*)(ws + OFF_AO);
    const u16* Bt = (const u16*)(ws + OFF_W + 3 * SZ_W);
    const float* bias = (const float*)(ws + OFF_BIAS) + 3 * D_;
    const int out_bf16 = *(const int*)(ws + OFF_FLAG);

    const int tid = threadIdx.x, lane = tid & 63, wave = tid >> 6;
    const int wm = (wave & 1) * 64, wn = (wave >> 1) * 64;
    const int m0 = blockIdx.y * 128, n0 = blockIdx.x * 128;
    const int lr = lane & 15, quad = lane >> 4, kq = quad * 8;
    const int srow = tid >> 2, scol = (tid & 3) * 8;

    f32x4 acc[4][4];
#pragma unroll
    for (int i = 0; i < 4; i++)
#pragma unroll
        for (int j = 0; j < 4; j++) acc[i][j] = (f32x4){0.f, 0.f, 0.f, 0.f};

    const u16* Ag0 = A  + (size_t)(m0 + srow)      * D_ + scol;
    const u16* Ag1 = A  + (size_t)(m0 + srow + 64) * D_ + scol;
    const u16* Bg0 = Bt + (size_t)(n0 + srow)      * D_ + scol;
    const u16* Bg1 = Bt + (size_t)(n0 + srow + 64) * D_ + scol;

    for (int k0 = 0; k0 < D_; k0 += 32) {
        glds16(Ag0 + k0, &As[tid * 8]);
        glds16(Ag1 + k0, &As[2048 + tid * 8]);
        glds16(Bg0 + k0, &Bs[tid * 8]);
        glds16(Bg1 + k0, &Bs[2048 + tid * 8]);
        __syncthreads();
        bf16x8 a[4], b[4];
#pragma unroll
        for (int i = 0; i < 4; i++) a[i] = *(const bf16x8*)&As[(wm + i * 16 + lr) * 32 + kq];
#pragma unroll
        for (int j = 0; j < 4; j++) b[j] = *(const bf16x8*)&Bs[(wn + j * 16 + lr) * 32 + kq];
#pragma unroll
        for (int i = 0; i < 4; i++)
#pragma unroll
            for (int j = 0; j < 4; j++) acc[i][j] = mfma16(a[i], b[j], acc[i][j]);
        __syncthreads();
    }
#pragma unroll
    for (int i = 0; i < 4; i++) {
        const int row_b = m0 + wm + i * 16 + quad * 4;
#pragma unroll
        for (int j = 0; j < 4; j++) {
            const int col = n0 + wn + j * 16 + lr;
            const float bv_ = bias[col];
#pragma unroll
            for (int r = 0; r < 4; r++) {
                const int row = row_b + r;
                const float v = acc[i][j][r] + bv_;
                const size_t idx = (size_t)row * D_ + col;
                if (out_bf16) ((u16*)dout)[idx] = f2bf(v);
                else          ((float*)dout)[idx] = v;
            }
        }
    }
}

extern "C" void kernel_launch(void* const* d_in, const int* in_sizes, int n_in,
                              void* d_out, int out_size, void* d_ws, size_t ws_size,
                              hipStream_t stream) {
    (void)in_sizes; (void)n_in; (void)out_size; (void)ws_size;
    const void* x  = d_in[0];
    const int* mask = (const int*)d_in[1];
    const void* wq = d_in[2]; const void* bq = d_in[3];
    const void* wk = d_in[4]; const void* bk = d_in[5];
    const void* wv = d_in[6]; const void* bv = d_in[7];
    const void* wo = d_in[8]; const void* bo = d_in[9];
    char* ws = (char*)d_ws;

    detect_kernel<<<dim3(1), dim3(256), 0, stream>>>(wq, ws);
    convert_kernel<<<dim3(2048), dim3(256), 0, stream>>>(x, wq, wk, wv, wo,
                                                         bq, bk, bv, bo, ws);
    qkv_gemm<<<dim3(8, 32, 3), dim3(256), 0, stream>>>(ws);
    attn_kernel<<<dim3(S_ / 64, B_ * H_), dim3(256), 0, stream>>>(ws, mask);
    out_gemm<<<dim3(8, 32), dim3(256), 0, stream>>>(ws, d_out);
}

// Round 2
// 243.144 us; speedup vs baseline: 1.2512x; 1.2512x over previous
//
#include <hip/hip_runtime.h>
#include <stdint.h>

#define B_   2
#define S_   2048
#define D_   1024
#define H_   16
#define HD_  64
#define NTOK (B_ * S_)   // 4096

typedef unsigned short u16;
typedef __bf16 bf16x8 __attribute__((ext_vector_type(8)));
typedef float  f32x4  __attribute__((ext_vector_type(4)));
typedef u16    u16x4  __attribute__((ext_vector_type(4)));

// ---- workspace layout (bytes) ----
#define OFF_FLAG ((size_t)0)
#define OFF_BIAS ((size_t)64)                       // 4*1024 fp32
#define OFF_MB   ((size_t)32768)                    // B*S fp32 mask bias (16 KB)
#define OFF_X    ((size_t)65536)
#define SZ_X     ((size_t)NTOK * D_ * 2)            // 8 MB
#define OFF_W    (OFF_X + SZ_X)
#define SZ_W     ((size_t)D_ * D_ * 2)
#define OFF_Q    (OFF_W + 4 * SZ_W)
#define SZ_T     SZ_X
#define OFF_K2   (OFF_Q + SZ_T)
#define OFF_VT   (OFF_K2 + SZ_T)
#define OFF_AO   (OFF_VT + SZ_T)

__device__ __forceinline__ float bf2f(u16 h) {
    union { uint32_t u; float f; } c; c.u = ((uint32_t)h) << 16; return c.f;
}
__device__ __forceinline__ u16 f2bf(float f) {
    union { float f; uint32_t u; } c; c.f = f;
    uint32_t r = c.u + 0x7fffu + ((c.u >> 16) & 1u);   // RNE
    return (u16)(r >> 16);
}
__device__ __forceinline__ void glds16(const u16* g, u16* l) {
    __builtin_amdgcn_global_load_lds(
        (const __attribute__((address_space(1))) uint32_t*)g,
        (__attribute__((address_space(3))) uint32_t*)l,
        16, 0, 0);
}
__device__ __forceinline__ f32x4 mfma16(bf16x8 a, bf16x8 b, f32x4 c) {
    return __builtin_amdgcn_mfma_f32_16x16x32_bf16(a, b, c, 0, 0, 0);
}

// ---- 1-block dtype detector: even-index bf16s of fp32 data are garbage ----
__global__ void detect_kernel(const void* wq, char* ws) {
    __shared__ int ok;
    if (threadIdx.x == 0) ok = 1;
    __syncthreads();
    const u16* p = (const u16*)wq;
    bool bad = false;
    for (int j = 0; j < 8; ++j) {
        float v = bf2f(p[(threadIdx.x * 8 + j) * 2]);
        if (!(v > -1.0f && v < 1.0f)) bad = true;
    }
    if (bad) ok = 0;
    __syncthreads();
    if (threadIdx.x == 0) *(int*)(ws + OFF_FLAG) = ok;  // 1 => data is bf16
}

// ---- normalize float tensors into ws; build fp32 mask-bias row ----
__global__ void convert_kernel(const void* x, const void* wq, const void* wk,
                               const void* wv, const void* wo,
                               const void* bq, const void* bk, const void* bv,
                               const void* bo, const int* mask, char* ws) {
    const int is_bf16 = *(const int*)(ws + OFF_FLAG);
    u16* Xd = (u16*)(ws + OFF_X);
    u16* Wd = (u16*)(ws + OFF_W);
    float* Bd = (float*)(ws + OFF_BIAS);
    float* Mbd = (float*)(ws + OFF_MB);
    const uint32_t NX = (uint32_t)NTOK * D_;     // 2^22
    const uint32_t NW = (uint32_t)D_ * D_;       // 2^20
    const uint32_t NB = 4u * D_;
    const uint32_t total = NX + 4 * NW + NB + (uint32_t)NTOK;
    for (uint32_t i = blockIdx.x * 256u + threadIdx.x; i < total;
         i += gridDim.x * 256u) {
        if (i < NX + 4 * NW) {
            const void* src; uint32_t si; u16* dst;
            if (i < NX) { src = x; si = i; dst = Xd + i; }
            else {
                uint32_t j = i - NX;
                uint32_t w = j >> 20; si = j & (NW - 1u);
                src = (w == 0) ? wq : (w == 1) ? wk : (w == 2) ? wv : wo;
                dst = Wd + j;
            }
            *dst = is_bf16 ? ((const u16*)src)[si] : f2bf(((const float*)src)[si]);
        } else if (i < NX + 4 * NW + NB) {
            uint32_t j = i - NX - 4 * NW;
            uint32_t w = j >> 10; uint32_t si = j & (D_ - 1u);
            const void* src = (w == 0) ? bq : (w == 1) ? bk : (w == 2) ? bv : bo;
            Bd[j] = is_bf16 ? bf2f(((const u16*)src)[si]) : ((const float*)src)[si];
        } else {
            uint32_t j = i - NX - 4 * NW - NB;
            Mbd[j] = (mask[j] == 0) ? -1.0e9f : 0.0f;
        }
    }
}

// ---- fused QKV projection (bt-GEMM, 128x128 tile, swizzled LDS) ----
// z=0 -> Q[b,h,s,hd] (pre-scaled 1/8); z=1 -> K[b,h,s,hd]; z=2 -> V^T[b,h,hd,s]
__global__ void qkv_gemm(char* ws) {
    __shared__ alignas(16) u16 As[128 * 32];
    __shared__ alignas(16) u16 Bs[128 * 32];
    const int z = blockIdx.z;
    const u16* A    = (const u16*)(ws + OFF_X);
    const u16* Bt   = (const u16*)(ws + OFF_W + (size_t)z * SZ_W);
    const float* bias = (const float*)(ws + OFF_BIAS) + z * D_;
    u16* Qd  = (u16*)(ws + OFF_Q);
    u16* Kd  = (u16*)(ws + OFF_K2);
    u16* Vtd = (u16*)(ws + OFF_VT);

    const int tid = threadIdx.x, lane = tid & 63, wave = tid >> 6;
    const int wm = (wave & 1) * 64, wn = (wave >> 1) * 64;
    const int m0 = blockIdx.y * 128, n0 = blockIdx.x * 128;
    const int lr = lane & 15, quad = lane >> 4;
    const int srow = tid >> 2;
    const int scol = (((tid & 3) ^ ((tid >> 3) & 3)) * 8);   // swizzled src chunk
    const int rd_off = (quad ^ ((lr >> 1) & 3)) * 8;         // swizzled read chunk

    f32x4 acc[4][4];
#pragma unroll
    for (int i = 0; i < 4; i++)
#pragma unroll
        for (int j = 0; j < 4; j++) acc[i][j] = (f32x4){0.f, 0.f, 0.f, 0.f};

    const u16* Ag0 = A  + (size_t)(m0 + srow)      * D_ + scol;
    const u16* Ag1 = A  + (size_t)(m0 + srow + 64) * D_ + scol;
    const u16* Bg0 = Bt + (size_t)(n0 + srow)      * D_ + scol;
    const u16* Bg1 = Bt + (size_t)(n0 + srow + 64) * D_ + scol;

    for (int k0 = 0; k0 < D_; k0 += 32) {
        glds16(Ag0 + k0, &As[tid * 8]);
        glds16(Ag1 + k0, &As[2048 + tid * 8]);
        glds16(Bg0 + k0, &Bs[tid * 8]);
        glds16(Bg1 + k0, &Bs[2048 + tid * 8]);
        __syncthreads();
        bf16x8 a[4], b[4];
#pragma unroll
        for (int i = 0; i < 4; i++) a[i] = *(const bf16x8*)&As[(wm + i * 16 + lr) * 32 + rd_off];
#pragma unroll
        for (int j = 0; j < 4; j++) b[j] = *(const bf16x8*)&Bs[(wn + j * 16 + lr) * 32 + rd_off];
#pragma unroll
        for (int i = 0; i < 4; i++)
#pragma unroll
            for (int j = 0; j < 4; j++) acc[i][j] = mfma16(a[i], b[j], acc[i][j]);
        __syncthreads();
    }
#pragma unroll
    for (int i = 0; i < 4; i++) {
        const int row_b = m0 + wm + i * 16 + quad * 4;
#pragma unroll
        for (int j = 0; j < 4; j++) {
            const int col = n0 + wn + j * 16 + lr;
            const float bv_ = bias[col];
            const int h = col >> 6, hd = col & 63;
            if (z == 2) {
                const int bb = row_b >> 11, s = row_b & 2047;
                u16x4 pk;
#pragma unroll
                for (int r = 0; r < 4; r++) pk[r] = f2bf(acc[i][j][r] + bv_);
                *(u16x4*)&Vtd[(((size_t)(bb * H_ + h)) * HD_ + hd) * S_ + s] = pk;
            } else {
#pragma unroll
                for (int r = 0; r < 4; r++) {
                    const int row = row_b + r;
                    const int bb = row >> 11, s = row & 2047;
                    const float v = acc[i][j][r] + bv_;
                    const size_t idx = (((size_t)(bb * H_ + h)) * S_ + s) * HD_ + hd;
                    if (z == 0) Qd[idx] = f2bf(v * 0.125f);
                    else        Kd[idx] = f2bf(v);
                }
            }
        }
    }
}

// ---- flash attention: 2 waves/block, 32 q/wave, 64-key tiles, swizzled LDS ----
__global__ void __launch_bounds__(128)
attn_kernel(char* ws) {
    __shared__ alignas(16) u16 Ks[64 * 64];     // [key][hd], chunk-swizzled
    __shared__ alignas(16) u16 Vts[64 * 64];    // [hd][key], chunk-swizzled
    __shared__ alignas(16) u16 Ps[2][32 * 64];  // per-wave P [q][key], swizzled

    const u16* Qb  = (const u16*)(ws + OFF_Q);
    const u16* Kb  = (const u16*)(ws + OFF_K2);
    const u16* Vtb = (const u16*)(ws + OFF_VT);
    const float* Mb = (const float*)(ws + OFF_MB);
    u16* AO = (u16*)(ws + OFF_AO);

    const int tid = threadIdx.x, lane = tid & 63, wave = tid >> 6;
    const int bh = blockIdx.y, b = bh >> 4, h = bh & 15;
    const int qb = blockIdx.x * 64 + wave * 32;
    const int lr = lane & 15, quad = lane >> 4;
    const int sx = lr & 7;                        // read-side swizzle key

    const u16* Qbh = Qb  + (size_t)bh * S_ * HD_;
    const u16* Kbh = Kb  + (size_t)bh * S_ * HD_;
    const u16* Vbh = Vtb + (size_t)bh * HD_ * S_;
    const float* Mbb = Mb + b * S_;

    // staging lane-constant indices (row r = tid>>3 (+16t), swizzled chunk)
    const int st_r = tid >> 3;
    const int st_c = (tid & 7) ^ (st_r & 7);

    bf16x8 qf[2][2];
#pragma unroll
    for (int s = 0; s < 2; ++s)
#pragma unroll
        for (int hf = 0; hf < 2; ++hf)
            qf[s][hf] = *(const bf16x8*)&Qbh[(size_t)(qb + s * 16 + lr) * HD_ + hf * 32 + quad * 8];

    float m_i[2] = {-1e30f, -1e30f}, l_i[2] = {0.f, 0.f};
    f32x4 oacc[2][4];
#pragma unroll
    for (int s = 0; s < 2; ++s)
#pragma unroll
        for (int j = 0; j < 4; ++j) oacc[s][j] = (f32x4){0.f, 0.f, 0.f, 0.f};

    u16* Pw = &Ps[wave][0];

    for (int kt = 0; kt < S_ / 64; ++kt) {
        const int k0 = kt * 64;
        const u16* Kt = Kbh + (size_t)(k0 + st_r) * HD_ + st_c * 8;
        const u16* Vt = Vbh + (size_t)st_r * S_ + k0 + st_c * 8;
#pragma unroll
        for (int t = 0; t < 4; ++t) {
            glds16(Kt + (size_t)t * 16 * HD_, &Ks[(tid + t * 128) * 8]);
            glds16(Vt + (size_t)t * 16 * S_,  &Vts[(tid + t * 128) * 8]);
        }
        __syncthreads();

        // S^T = K Q^T : A=K (m=key), B=Q (n=query); C col=query, rows=keys
        f32x4 sc[2][4];
#pragma unroll
        for (int j = 0; j < 4; ++j) {
            const int krow = (j * 16 + lr) * 64;
            bf16x8 kfA = *(const bf16x8*)&Ks[krow + ((quad    ) ^ sx) * 8];
            bf16x8 kfB = *(const bf16x8*)&Ks[krow + ((quad + 4) ^ sx) * 8];
            f32x4 mb = *(const f32x4*)&Mbb[k0 + j * 16 + quad * 4];
#pragma unroll
            for (int s = 0; s < 2; ++s) {
                f32x4 t0 = mfma16(kfA, qf[s][0], (f32x4){0.f, 0.f, 0.f, 0.f});
                t0 = mfma16(kfB, qf[s][1], t0);
                sc[s][j] = t0 + mb;
            }
        }
        // V fragments (shared across both q-strips)
        bf16x8 vf[4][2];
#pragma unroll
        for (int j2 = 0; j2 < 4; ++j2) {
            const int vrow = (j2 * 16 + lr) * 64;
            vf[j2][0] = *(const bf16x8*)&Vts[vrow + ((quad    ) ^ sx) * 8];
            vf[j2][1] = *(const bf16x8*)&Vts[vrow + ((quad + 4) ^ sx) * 8];
        }

#pragma unroll
        for (int s = 0; s < 2; ++s) {
            float mx = -1e30f;
#pragma unroll
            for (int j = 0; j < 4; ++j)
#pragma unroll
                for (int r = 0; r < 4; ++r) mx = fmaxf(mx, sc[s][j][r]);
            mx = fmaxf(mx, __shfl_xor(mx, 16, 64));
            mx = fmaxf(mx, __shfl_xor(mx, 32, 64));
            const float mnew = fmaxf(m_i[s], mx);
            const float alpha = __expf(m_i[s] - mnew);

            const int prow = (s * 16 + lr) * 64;
            f32x4 rs4 = (f32x4){0.f, 0.f, 0.f, 0.f};
#pragma unroll
            for (int j = 0; j < 4; ++j) {
                f32x4 p;
#pragma unroll
                for (int r = 0; r < 4; ++r) p[r] = __expf(sc[s][j][r] - mnew);
                rs4 += p;
                u16x4 pk;
#pragma unroll
                for (int r = 0; r < 4; ++r) pk[r] = f2bf(p[r]);
                *(u16x4*)&Pw[prow + (((2 * j + (quad >> 1)) ^ sx) * 8) + (quad & 1) * 4] = pk;
            }
            float rs = (rs4[0] + rs4[1]) + (rs4[2] + rs4[3]);
            rs += __shfl_xor(rs, 16, 64);
            rs += __shfl_xor(rs, 32, 64);
            l_i[s] = l_i[s] * alpha + rs;
            m_i[s] = mnew;

#pragma unroll
            for (int r = 0; r < 4; ++r) {
                const float ab = __shfl(alpha, ((lane >> 4) << 2) + r, 64);
                oacc[s][0][r] *= ab; oacc[s][1][r] *= ab;
                oacc[s][2][r] *= ab; oacc[s][3][r] *= ab;
            }
            // P (A-layout) from wave-private LDS; PV accumulate
            bf16x8 pf0 = *(const bf16x8*)&Pw[prow + ((quad    ) ^ sx) * 8];
            bf16x8 pf1 = *(const bf16x8*)&Pw[prow + ((quad + 4) ^ sx) * 8];
#pragma unroll
            for (int j2 = 0; j2 < 4; ++j2) {
                oacc[s][j2] = mfma16(pf0, vf[j2][0], oacc[s][j2]);
                oacc[s][j2] = mfma16(pf1, vf[j2][1], oacc[s][j2]);
            }
        }
        __syncthreads();
    }
#pragma unroll
    for (int s = 0; s < 2; ++s) {
        const float linv = 1.0f / l_i[s];
#pragma unroll
        for (int r = 0; r < 4; ++r) {
            const float lb = __shfl(linv, ((lane >> 4) << 2) + r, 64);
            const int q = qb + s * 16 + quad * 4 + r;
            u16* dst = AO + (size_t)(b * S_ + q) * D_ + h * HD_;
#pragma unroll
            for (int j2 = 0; j2 < 4; ++j2)
                dst[j2 * 16 + lr] = f2bf(oacc[s][j2][r] * lb);
        }
    }
}

// ---- output projection: out = AO . Wo^T + bo (store per dtype flag) ----
__global__ void out_gemm(char* ws, void* dout) {
    __shared__ alignas(16) u16 As[128 * 32];
    __shared__ alignas(16) u16 Bs[128 * 32];
    const u16* A  = (const u16*)(ws + OFF_AO);
    const u16* Bt = (const u16*)(ws + OFF_W + 3 * SZ_W);
    const float* bias = (const float*)(ws + OFF_BIAS) + 3 * D_;
    const int out_bf16 = *(const int*)(ws + OFF_FLAG);

    const int tid = threadIdx.x, lane = tid & 63, wave = tid >> 6;
    const int wm = (wave & 1) * 64, wn = (wave >> 1) * 64;
    const int m0 = blockIdx.y * 128, n0 = blockIdx.x * 128;
    const int lr = lane & 15, quad = lane >> 4;
    const int srow = tid >> 2;
    const int scol = (((tid & 3) ^ ((tid >> 3) & 3)) * 8);
    const int rd_off = (quad ^ ((lr >> 1) & 3)) * 8;

    f32x4 acc[4][4];
#pragma unroll
    for (int i = 0; i < 4; i++)
#pragma unroll
        for (int j = 0; j < 4; j++) acc[i][j] = (f32x4){0.f, 0.f, 0.f, 0.f};

    const u16* Ag0 = A  + (size_t)(m0 + srow)      * D_ + scol;
    const u16* Ag1 = A  + (size_t)(m0 + srow + 64) * D_ + scol;
    const u16* Bg0 = Bt + (size_t)(n0 + srow)      * D_ + scol;
    const u16* Bg1 = Bt + (size_t)(n0 + srow + 64) * D_ + scol;

    for (int k0 = 0; k0 < D_; k0 += 32) {
        glds16(Ag0 + k0, &As[tid * 8]);
        glds16(Ag1 + k0, &As[2048 + tid * 8]);
        glds16(Bg0 + k0, &Bs[tid * 8]);
        glds16(Bg1 + k0, &Bs[2048 + tid * 8]);
        __syncthreads();
        bf16x8 a[4], b[4];
#pragma unroll
        for (int i = 0; i < 4; i++) a[i] = *(const bf16x8*)&As[(wm + i * 16 + lr) * 32 + rd_off];
#pragma unroll
        for (int j = 0; j < 4; j++) b[j] = *(const bf16x8*)&Bs[(wn + j * 16 + lr) * 32 + rd_off];
#pragma unroll
        for (int i = 0; i < 4; i++)
#pragma unroll
            for (int j = 0; j < 4; j++) acc[i][j] = mfma16(a[i], b[j], acc[i][j]);
        __syncthreads();
    }
#pragma unroll
    for (int i = 0; i < 4; i++) {
        const int row_b = m0 + wm + i * 16 + quad * 4;
#pragma unroll
        for (int j = 0; j < 4; j++) {
            const int col = n0 + wn + j * 16 + lr;
            const float bv_ = bias[col];
#pragma unroll
            for (int r = 0; r < 4; r++) {
                const int row = row_b + r;
                const float v = acc[i][j][r] + bv_;
                const size_t idx = (size_t)row * D_ + col;
                if (out_bf16) ((u16*)dout)[idx] = f2bf(v);
                else          ((float*)dout)[idx] = v;
            }
        }
    }
}

extern "C" void kernel_launch(void* const* d_in, const int* in_sizes, int n_in,
                              void* d_out, int out_size, void* d_ws, size_t ws_size,
                              hipStream_t stream) {
    (void)in_sizes; (void)n_in; (void)out_size; (void)ws_size;
    const void* x  = d_in[0];
    const int* mask = (const int*)d_in[1];
    const void* wq = d_in[2]; const void* bq = d_in[3];
    const void* wk = d_in[4]; const void* bk = d_in[5];
    const void* wv = d_in[6]; const void* bv = d_in[7];
    const void* wo = d_in[8]; const void* bo = d_in[9];
    char* ws = (char*)d_ws;

    detect_kernel<<<dim3(1), dim3(256), 0, stream>>>(wq, ws);
    convert_kernel<<<dim3(2048), dim3(256), 0, stream>>>(x, wq, wk, wv, wo,
                                                         bq, bk, bv, bo, mask, ws);
    qkv_gemm<<<dim3(8, 32, 3), dim3(256), 0, stream>>>(ws);
    attn_kernel<<<dim3(S_ / 64, B_ * H_), dim3(128), 0, stream>>>(ws);
    out_gemm<<<dim3(8, 32), dim3(256), 0, stream>>>(ws, d_out);
}